// Round 5
// baseline (189.509 us; speedup 1.0000x reference)
//
#include <hip/hip_runtime.h>
#include <hip/hip_bf16.h>

typedef unsigned short u16;
typedef u16 us4 __attribute__((ext_vector_type(4)));
typedef u16 us8 __attribute__((ext_vector_type(8)));
typedef __bf16 bf16x8 __attribute__((ext_vector_type(8)));
typedef float f32x4 __attribute__((ext_vector_type(4)));

#define NDIM 4096
#define HDIM 2048

__device__ __forceinline__ u16 bfbits(float f) {
    __hip_bfloat16 h = __float2bfloat16(f);
    return __builtin_bit_cast(u16, h);
}
__device__ __forceinline__ float bf2f(u16 b) {
    return __builtin_bit_cast(float, ((unsigned)b) << 16);
}

__device__ __forceinline__ void gload_lds16(const u16* g, u16* l) {
    __builtin_amdgcn_global_load_lds((__attribute__((address_space(1))) void*)g,
                                     (__attribute__((address_space(3))) void*)l,
                                     16, 0, 0);
}

// ---------------------------------------------------------------------------
// Ce[u][k'] = cos(pi*k'*(u+0.5)/2048), Co[u][k'] = cos(pi*(2k'+1)*(u+0.5)/4096)
__global__ __launch_bounds__(256) void k_gencos2(u16* __restrict__ Ce, u16* __restrict__ Co) {
    int idx = blockIdx.x * 256 + threadIdx.x;
    int u = idx >> 8;
    int k0 = (idx & 255) * 8;
    unsigned step = (unsigned)(2 * u + 1);
    us8 e, o;
#pragma unroll
    for (int i = 0; i < 8; ++i) {
        unsigned kk = (unsigned)(k0 + i);
        unsigned te = (2u * kk * step) & 16383u;
        unsigned to = ((2u * kk + 1u) * step) & 16383u;
        e[i] = bfbits(cosf((float)te * 3.8349519697141029e-4f)); // 2pi/16384
        o[i] = bfbits(cosf((float)to * 3.8349519697141029e-4f));
    }
    *(us8*)&Ce[(size_t)idx * 8] = e;
    *(us8*)&Co[(size_t)idx * 8] = o;
}

// ---------------------------------------------------------------------------
// Xe[j][k'] = bf16(X[2k'][j]), Xo[j][k'] = bf16(X[2k'+1][j])
__global__ __launch_bounds__(256) void k_transpose_split(const float* __restrict__ X,
                                                         u16* __restrict__ Xe,
                                                         u16* __restrict__ Xo) {
    __shared__ float tile[64][65];
    int b  = blockIdx.x;
    int bx = (b & 63) * 64;
    int by = (b >> 6) * 64;
    int t  = threadIdx.x;
    int lr = t >> 4, lc = (t & 15) * 4;
#pragma unroll
    for (int r = 0; r < 64; r += 16) {
        float4 v = *(const float4*)&X[(size_t)(by + lr + r) * NDIM + bx + lc];
        tile[lr + r][lc + 0] = v.x;
        tile[lr + r][lc + 1] = v.y;
        tile[lr + r][lc + 2] = v.z;
        tile[lr + r][lc + 3] = v.w;
    }
    __syncthreads();
    int jl = t >> 2;
    int s8 = (t & 3) * 8;
    us8 e, o;
#pragma unroll
    for (int i = 0; i < 8; ++i) {
        e[i] = bfbits(tile[2 * (s8 + i)][jl]);
        o[i] = bfbits(tile[2 * (s8 + i) + 1][jl]);
    }
    size_t base = (size_t)(bx + jl) * HDIM + (by >> 1) + s8;
    *(us8*)&Xe[base] = e;
    *(us8*)&Xo[base] = o;
}

// ---------------------------------------------------------------------------
// Butterfly 1: W[u] = S[u]+D[u], W[4095-u] = S[u]-D[u], column-deinterleaved.
__global__ __launch_bounds__(256) void k_bfly1(const u16* __restrict__ S,
                                               const u16* __restrict__ D,
                                               u16* __restrict__ We,
                                               u16* __restrict__ Wo) {
    int idx = blockIdx.x * 256 + threadIdx.x;
    int u  = idx >> 9;
    int j0 = (idx & 511) * 8;
    us8 s8 = *(const us8*)&S[(size_t)u * NDIM + j0];
    us8 d8 = *(const us8*)&D[(size_t)u * NDIM + j0];
    us4 et, ot, eb, ob;
#pragma unroll
    for (int i = 0; i < 4; ++i) {
        float se = bf2f(s8[2 * i]),     de = bf2f(d8[2 * i]);
        float so = bf2f(s8[2 * i + 1]), dd = bf2f(d8[2 * i + 1]);
        et[i] = bfbits(se + de);  eb[i] = bfbits(se - de);
        ot[i] = bfbits(so + dd);  ob[i] = bfbits(so - dd);
    }
    size_t ct = (size_t)u * HDIM + (j0 >> 1);
    size_t cb = (size_t)(NDIM - 1 - u) * HDIM + (j0 >> 1);
    *(us4*)&We[ct] = et;  *(us4*)&Wo[ct] = ot;
    *(us4*)&We[cb] = eb;  *(us4*)&Wo[cb] = ob;
}

// ---------------------------------------------------------------------------
// Butterfly 2: Y[i][v'] = S2+D2, Y[i][4095-v'] = S2-D2, f32 out.
__global__ __launch_bounds__(256) void k_bfly2(const u16* __restrict__ S2,
                                               const u16* __restrict__ D2,
                                               float* __restrict__ Y) {
    int idx = blockIdx.x * 256 + threadIdx.x;
    int i  = idx >> 8;
    int v0 = (idx & 255) * 8;
    us8 s8 = *(const us8*)&S2[(size_t)i * HDIM + v0];
    us8 d8 = *(const us8*)&D2[(size_t)i * HDIM + v0];
    float sum[8], dif[8];
#pragma unroll
    for (int t = 0; t < 8; ++t) {
        float s = bf2f(s8[t]), d = bf2f(d8[t]);
        sum[t] = s + d;  dif[t] = s - d;
    }
    f32x4 a0, a1, r0, r1;
#pragma unroll
    for (int w = 0; w < 4; ++w) {
        a0[w] = sum[w];  a1[w] = sum[w + 4];
        r0[w] = dif[7 - w];  r1[w] = dif[3 - w];
    }
    float* row = Y + (size_t)i * NDIM;
    *(f32x4*)&row[v0]        = a0;
    *(f32x4*)&row[v0 + 4]    = a1;
    *(f32x4*)&row[4088 - v0] = r0;
    *(f32x4*)&row[4092 - v0] = r1;
}

// ---------------------------------------------------------------------------
// D = A @ B^T, 256x256 tile, BK=64, 8 waves, 8-phase schedule, 3-half-deep
// counted-vmcnt pipeline + one-phase-ahead ds_read prefetch.
// Phase MFMA quadrants: (m-half, k-half): ph1(m0-3,k0) ph2(m4-7,k0)
// ph3(m0-3,k1) ph4(m4-7,k1) -> per-acc K order unchanged (bitwise-same out).
// Staging halves (unchanged, proven r4 ledger):
//   A-h0' = rows [0,64)+[128,192), A-h1' = complement
//   B-h0' = rows wc*64+[0,32) all wc, B-h1' = complement
#define BAR() do { asm volatile("" ::: "memory"); __builtin_amdgcn_s_barrier(); \
                   asm volatile("" ::: "memory"); } while (0)
#define WAITV(N) asm volatile("s_waitcnt vmcnt(" #N ")" ::: "memory")

template <int NTK, int LOG_NTN>
__global__ __launch_bounds__(512, 2) void gemm256h(const u16* __restrict__ A0,
                                                   const u16* __restrict__ A1,
                                                   const u16* __restrict__ B0,
                                                   const u16* __restrict__ B1,
                                                   u16* __restrict__ out) {
    constexpr int KD  = NTK * 64;
    constexpr int NTN = 1 << LOG_NTN;
    constexpr int LDC = NTN * 256;
    constexpr int MTILES = 128 >> LOG_NTN;

    __shared__ u16 As[2 * 256 * 64];
    __shared__ u16 Bs[2 * 256 * 64];

    const int tid  = threadIdx.x;
    const int wave = tid >> 6;
    const int lane = tid & 63;

    const int bid = blockIdx.x;
    const int swz = (bid & 7) * 32 + (bid >> 3);   // grid 256, bijective
    const int half = swz >> 7;
    const int r    = swz & 127;
    const int bm   = (r >> LOG_NTN) * 256;
    const int bn   = (r & (NTN - 1)) * 256;

    const u16* A = half ? A1 : A0;
    const u16* B = half ? B1 : B0;
    u16* Cp = out + (size_t)half * MTILES * 256 * LDC;

    const int wr = wave >> 2;
    const int wc = wave & 3;

    const int srow = lane >> 3;
    const int scol = ((lane & 7) ^ srow) << 3;     // pre-swizzled global col offset

    const int fr   = lane & 15;
    const int hi   = lane >> 4;
    const int slot0 = ((hi)     ^ (lane & 7)) << 3;   // k-half 0
    const int slot1 = ((hi + 4) ^ (lane & 7)) << 3;   // k-half 1
    const int aRow = (wr * 128 + fr) * 64;
    const int bRow = (wc * 64 + fr) * 64;

    f32x4 acc[8][4] = {};
    bf16x8 a0r[4], a1r[4], bb0[4], bb1[4];   // m0-3 / m4-7 A frags; k0 / k1 B frags

#define STAGE_A(TK, H, BOFF)                                                     \
    do {                                                                         \
        const int _tk = (TK) & (NTK - 1);                                        \
        _Pragma("unroll")                                                        \
        for (int q = 0; q < 2; ++q) {                                            \
            const int seg  = wave * 2 + q;                                       \
            const int row0 = (H) * 64 + (seg & 7) * 8 + (seg >> 3) * 128;        \
            const u16* _g = A + (size_t)(bm + row0 + srow) * KD + _tk * 64 + scol; \
            gload_lds16(_g, As + (BOFF) + row0 * 64 + lane * 8);                 \
        }                                                                        \
    } while (0)

#define STAGE_B(TK, H, BOFF)                                                     \
    do {                                                                         \
        const int _tk = (TK) & (NTK - 1);                                        \
        _Pragma("unroll")                                                        \
        for (int q = 0; q < 2; ++q) {                                            \
            const int seg  = wave * 2 + q;                                       \
            const int row0 = (H) * 32 + (seg & 3) * 8 + (seg >> 2) * 64;         \
            const u16* _g = B + (size_t)(bn + row0 + srow) * KD + _tk * 64 + scol; \
            gload_lds16(_g, Bs + (BOFF) + row0 * 64 + lane * 8);                 \
        }                                                                        \
    } while (0)

// read 4 A frags (m-block MB..MB+3) at k-half slot SL into DST
#define RD_A(DST, MB, SL, BOFF)                                                 \
    _Pragma("unroll")                                                           \
    for (int mm = 0; mm < 4; ++mm)                                              \
        DST[mm] = __builtin_bit_cast(bf16x8, *(const us8*)(As + (BOFF) + aRow + ((MB) + mm) * 1024 + (SL)));

// read 4 B frags (n0..n3) at k-half slot SL into DST
#define RD_B(DST, SL, BOFF)                                                     \
    _Pragma("unroll")                                                           \
    for (int nn = 0; nn < 4; ++nn)                                              \
        DST[nn] = __builtin_bit_cast(bf16x8, *(const us8*)(Bs + (BOFF) + bRow + nn * 1024 + (SL)));

// 16 MFMAs: acc rows MB..MB+3, all 4 n, one k-half
#define MFMA16(MB, AREG, BREG)                                                  \
    do {                                                                        \
        __builtin_amdgcn_s_setprio(1);                                          \
        _Pragma("unroll")                                                       \
        for (int mm = 0; mm < 4; ++mm)                                          \
            _Pragma("unroll")                                                   \
            for (int nn = 0; nn < 4; ++nn)                                      \
                acc[(MB)+mm][nn] = __builtin_amdgcn_mfma_f32_16x16x32_bf16(AREG[mm], BREG[nn], acc[(MB)+mm][nn], 0, 0, 0); \
        __builtin_amdgcn_s_setprio(0);                                          \
    } while (0)

    // ---- prologue: 7 halves (r4 ledger); vmcnt(6) completes tile 0; preload ph1 operands
    STAGE_B(0, 0, 0);
    STAGE_A(0, 0, 0);
    STAGE_B(0, 1, 0);
    STAGE_A(0, 1, 0);
    STAGE_B(1, 0, 16384);
    STAGE_A(1, 0, 16384);
    STAGE_B(1, 1, 16384);
    WAITV(6);
    BAR();
    RD_A(a0r, 0, slot0, 0);    // m0-3, k0, buf0
    RD_B(bb0, slot0, 0);       // n0-3, k0, buf0

    for (int t = 0; t < NTK; t += 2) {
        // ph1: MFMA(m0-3,k0) buf0; stage A(t+1)h1'->buf1; prefetch a1(k0), bb1(k1)
        STAGE_A(t + 1, 1, 16384);
        BAR();
        MFMA16(0, a0r, bb0);
        RD_A(a1r, 4, slot0, 0);
        RD_B(bb1, slot1, 0);
        BAR();
        // ph2: MFMA(m4-7,k0); stage B(t+2)h0'->buf0; prefetch a0(k1)
        STAGE_B(t + 2, 0, 0);
        BAR();
        MFMA16(4, a1r, bb0);
        RD_A(a0r, 0, slot1, 0);
        BAR();
        // ph3: MFMA(m0-3,k1); stage A(t+2)h0'->buf0; prefetch a1(k1)
        STAGE_A(t + 2, 0, 0);
        BAR();
        MFMA16(0, a0r, bb1);
        RD_A(a1r, 4, slot1, 0);
        BAR();
        // ph4: MFMA(m4-7,k1); stage B(t+2)h1'->buf0; WAITV(6) completes tile t+1;
        //      prefetch next tile's a0(k0), bb0(k0) from buf1
        STAGE_B(t + 2, 1, 0);
        BAR();
        MFMA16(4, a1r, bb1);
        WAITV(6);
        RD_A(a0r, 0, slot0, 16384);
        RD_B(bb0, slot0, 16384);
        BAR();
        // ph5..ph8: mirror with buffers swapped (tile t+1 in buf1)
        STAGE_A(t + 2, 1, 0);
        BAR();
        MFMA16(0, a0r, bb0);
        RD_A(a1r, 4, slot0, 16384);
        RD_B(bb1, slot1, 16384);
        BAR();
        STAGE_B(t + 3, 0, 16384);
        BAR();
        MFMA16(4, a1r, bb0);
        RD_A(a0r, 0, slot1, 16384);
        BAR();
        STAGE_A(t + 3, 0, 16384);
        BAR();
        MFMA16(0, a0r, bb1);
        RD_A(a1r, 4, slot1, 16384);
        BAR();
        STAGE_B(t + 3, 1, 16384);
        BAR();
        MFMA16(4, a1r, bb1);
        WAITV(6);
        RD_A(a0r, 0, slot0, 0);
        RD_B(bb0, slot0, 0);
        BAR();
    }

    asm volatile("s_waitcnt vmcnt(0)" ::: "memory");

    const int orow0 = wr * 128 + hi * 4;
    const int ocol0 = bn + wc * 64 + fr;
#pragma unroll
    for (int m = 0; m < 8; ++m)
#pragma unroll
        for (int n = 0; n < 4; ++n) {
            f32x4 v = acc[m][n];
#pragma unroll
            for (int rr = 0; rr < 4; ++rr) {
                size_t off = (size_t)(bm + orow0 + m * 16 + rr) * LDC + (ocol0 + n * 16);
                Cp[off] = bfbits(v[rr]);
            }
        }
#undef STAGE_A
#undef STAGE_B
#undef RD_A
#undef RD_B
#undef MFMA16
}

// ---------------------------------------------------------------------------
extern "C" void kernel_launch(void* const* d_in, const int* in_sizes, int n_in,
                              void* d_out, int out_size, void* d_ws, size_t ws_size,
                              hipStream_t stream) {
    const float* X = (const float*)d_in[0];
    float* Y = (float*)d_out;

    const size_t QM = (size_t)HDIM * HDIM;
    u16* Ce = (u16*)d_ws;
    u16* Co = Ce + QM;
    u16* Xe = Co + QM;
    u16* Xo = Xe + 2 * QM;
    u16* S  = Xo + 2 * QM;
    u16* D  = S + 2 * QM;
    u16* We = Xe;
    u16* Wo = Xo;
    u16* S2 = S;
    u16* D2 = D;

    k_gencos2<<<2048, 256, 0, stream>>>(Ce, Co);
    k_transpose_split<<<4096, 256, 0, stream>>>(X, Xe, Xo);
    gemm256h<32, 4><<<256, 512, 0, stream>>>(Ce, Co, Xe, Xo, S);
    k_bfly1<<<4096, 256, 0, stream>>>(S, D, We, Wo);
    gemm256h<32, 3><<<256, 512, 0, stream>>>(We, Wo, Ce, Co, S2);
    k_bfly2<<<4096, 256, 0, stream>>>(S2, D2, Y);
}